// Round 4
// baseline (483.591 us; speedup 1.0000x reference)
//
#include <hip/hip_runtime.h>

// Laplacian-kernel regression, fused, bf16 MFMA (QK 32x32x16, PV 16x16x32).
//   d2 = ||x||^2 + ||z||^2 - 2 X.Z^T ; P = exp(-sqrt(d2)/10) ; out = P @ W
// R15: occupancy WITHOUT reuse loss. v13/v14 lesson: wave tile must be
// 64x64 (reuse 2x2, acc 128 regs) and every Z/W frag loaded by exactly one
// wave, else L2 floor doubles (v14: 93us floor, MfmaUtil 28). Only config
// with >2 waves/SIMD under those constraints: 256 thr, 3 blocks/CU
// (launch_bounds(256,3), cap 168 regs). LDS cut 65.8->50.2 KB:
//  * X staged as ping-pong 128-k quarters (2x16 KB, async gload_lds,
//    stage issued at quarter start, consumed next quarter).
//  * sP as two 64x136 z-halves (17.4 KB); PV in 2 passes (waves 0,1 write
//    half0, PV1, waves 2,3 write half1, PV2). PV uses 16x16x32 MFMA so
//    sP reads keep v11's conflict-free 16-row pattern.
//  * P packed to bf16 in regs post-QK (frees 48 regs before PV).
// 7 barriers/mt, all cheap; 3 blocks/CU = 3 barrier domains interleave.
// L2 total ~1.8 GB -> 52us floor; MFMA floor 45us.

using frag8  = __attribute__((ext_vector_type(8)))  short;   // 8 bf16 (4 VGPRs)
using f32x4  = __attribute__((ext_vector_type(4)))  float;   // 16x16 C/D frag
using f32x16 = __attribute__((ext_vector_type(16))) float;   // 32x32 C/D frag

constexpr int Nn = 8192, Mm = 8192, Dd = 512, Yd = 256;
constexpr int BM = 64, BN = 256;
constexpr int MCH = 4, MPER = Mm / MCH, MT = MPER / BN;    // 2048, 8
constexpr int LDPH = 136;   // sP half row stride (128 z + 8 pad), 272B

// Fragment-tile layout (16-row groups, unchanged from prep_v11):
// frag(g, c) = rows [16g,16g+16) x k [32c,32c+32), 512 ushorts at
// (g*KG + c)*512, element (r,k) at ushort lane16*8 + k%8 where
// lane16 = r%16 + 16*((k%32)/8).  Xf/Zf: KG=16 (K=512). Wf: rows=y, KG=256.
// 32x32x16 A/B-frag for lane L (r=L&31, h=L>>5) = one 16B chunk at
// base + kw*256 ushorts.  16x16x32 A/B-frag = full unit, lane*8.

// workspace layout (bytes)
constexpr size_t OFF_XF  = 0;                               // 8 MB
constexpr size_t OFF_ZF  = OFF_XF + (size_t)Nn * Dd * 2;    // 8 MB
constexpr size_t OFF_WF  = OFF_ZF + (size_t)Mm * Dd * 2;    // 4 MB
constexpr size_t OFF_XSQ = OFF_WF + (size_t)Yd * Mm * 2;
constexpr size_t OFF_ZSQ = OFF_XSQ + (size_t)Nn * 4;
constexpr size_t WS_NEED = OFF_ZSQ + (size_t)Mm * 4;        // ~20.1 MB

__device__ __forceinline__ ushort f2bf(float f) {
    unsigned u = __builtin_bit_cast(unsigned, f);
    u += 0x7FFFu + ((u >> 16) & 1u);          // RNE (prep only)
    return (ushort)(u >> 16);
}

__device__ __forceinline__ void gload_lds16(const ushort* g, ushort* l) {
    __builtin_amdgcn_global_load_lds(
        (const __attribute__((address_space(1))) unsigned int*)(g),
        (__attribute__((address_space(3))) unsigned int*)(l), 16, 0, 0);
}

// ---- prep (LDS-tiled, coalesced) — unchanged from v11 ----
__global__ __launch_bounds__(256) void prep_v11(
    const float* __restrict__ X, const float* __restrict__ Z,
    const float* __restrict__ W, ushort* __restrict__ Xf,
    ushort* __restrict__ Zf, ushort* __restrict__ Wf,
    float* __restrict__ xsq, float* __restrict__ zsq)
{
    __shared__ float tile[8320];                  // 16x517 (X/Z) or 32x260 (W)
    __shared__ float part[256];
    const int t = threadIdx.x, b = blockIdx.x;
    if (b < 1024) {
        const int g = (b < 512) ? b : b - 512;
        const float* src = (b < 512 ? X : Z) + (size_t)g * 16 * Dd;
        ushort* dst = (b < 512 ? Xf : Zf) + (size_t)g * 16 * 512;
        float* nrm = (b < 512 ? xsq : zsq) + g * 16;
        #pragma unroll
        for (int rep = 0; rep < 8; ++rep) {       // 2048 float4, coalesced
            const int idx = rep * 256 + t;
            const int r = idx >> 7, c4 = (idx & 127) * 4;
            const float4 v = *(const float4*)(src + (size_t)r * Dd + c4);
            float* d = tile + r * 517 + c4;
            d[0] = v.x; d[1] = v.y; d[2] = v.z; d[3] = v.w;
        }
        __syncthreads();
        {
            const int r = t & 15, s0 = (t >> 4) * 32;
            float sq = 0.0f;
            #pragma unroll
            for (int k = 0; k < 32; ++k) {
                const float v = tile[r * 517 + s0 + k];
                sq += v * v;
            }
            part[t] = sq;
        }
        __syncthreads();
        if (t < 16) {
            float sq = 0.0f;
            #pragma unroll
            for (int s = 0; s < 16; ++s) sq += part[t + 16 * s];
            nrm[t] = sq;
        }
        #pragma unroll
        for (int rep = 0; rep < 4; ++rep) {       // 1024 uint4 frag writes
            const int idx = rep * 256 + t;
            const int kg = idx >> 6, w = idx & 63;
            const int l16 = w & 15, quad = w >> 4;
            const float* s = tile + l16 * 517 + kg * 32 + quad * 8;
            uint4 pk;
            pk.x = (unsigned)f2bf(s[0]) | ((unsigned)f2bf(s[1]) << 16);
            pk.y = (unsigned)f2bf(s[2]) | ((unsigned)f2bf(s[3]) << 16);
            pk.z = (unsigned)f2bf(s[4]) | ((unsigned)f2bf(s[5]) << 16);
            pk.w = (unsigned)f2bf(s[6]) | ((unsigned)f2bf(s[7]) << 16);
            *(uint4*)(dst + (size_t)kg * 512 + w * 8) = pk;
        }
    } else {
        const int zg = b - 1024;                  // 32-z stripe of W
        const float* src = W + (size_t)zg * 32 * Yd;
        #pragma unroll
        for (int rep = 0; rep < 8; ++rep) {
            const int idx = rep * 256 + t;
            const int r = idx >> 6, c4 = (idx & 63) * 4;
            const float4 v = *(const float4*)(src + (size_t)r * Yd + c4);
            float* d = tile + r * 260 + c4;
            d[0] = v.x; d[1] = v.y; d[2] = v.z; d[3] = v.w;
        }
        __syncthreads();
        #pragma unroll
        for (int rep = 0; rep < 4; ++rep) {
            const int idx = rep * 256 + t;
            const int yg = idx >> 6, w = idx & 63;
            const int l16 = w & 15, quad = w >> 4;
            const int y = yg * 16 + l16;
            ushort rr[8];
            #pragma unroll
            for (int j = 0; j < 8; ++j)
                rr[j] = f2bf(tile[(quad * 8 + j) * 260 + y]);
            uint4 pk;
            pk.x = (unsigned)rr[0] | ((unsigned)rr[1] << 16);
            pk.y = (unsigned)rr[2] | ((unsigned)rr[3] << 16);
            pk.z = (unsigned)rr[4] | ((unsigned)rr[5] << 16);
            pk.w = (unsigned)rr[6] | ((unsigned)rr[7] << 16);
            *(uint4*)(Wf + ((size_t)yg * 256 + zg) * 512 + w * 8) = pk;
        }
    }
}

// ---- main fused kernel (v15): 256 threads, 4 waves, 3 blocks/CU ----
__global__ __launch_bounds__(256, 3) void laplace_v15(
    const ushort* __restrict__ Xf, const ushort* __restrict__ Zf,
    const ushort* __restrict__ Wf, const float* __restrict__ xsqg,
    const float* __restrict__ zsqg, float* __restrict__ O)
{
    __shared__ ushort sM[25088];                  // 50,176 B
    ushort* const Xb0 = sM;                       // X quarter ping  (16 KB)
    ushort* const Xb1 = sM + 8192;                // X quarter pong  (16 KB)
    ushort* const sPh = sM + 16384;               // sP z-half 64x136 (17.4 KB)

    const int t = threadIdx.x, wid = t >> 6, lane = t & 63;
    const int l32 = lane & 31, hb = lane >> 5;
    const int l16 = lane & 15, quad = lane >> 4;

    // XCD-aware swizzle: z-chunk pinned to an XCD pair (grid = 512, 1-D)
    const int bid = blockIdx.x;
    const int xcd = bid & 7;
    const int chunk = xcd >> 1;                   // 0..3
    const int xi = ((xcd & 1) << 6) + (bid >> 3); // 0..127
    const int row0 = xi * BM;
    const int zbase = chunk * MPER;
    const int xg0 = row0 >> 4;

    const unsigned lane_lo = (unsigned)((l32 & 15) * 8 + hb * 128);
    // X A-frag lane offset within a quarter buffer (+ i*4096 + kwl*256)
    const int xlane = (l32 >> 4) * 2048 + (l32 & 15) * 8 + hb * 128;

    auto STAGE = [&](int srcq, ushort* nb) {      // stage one 128-k X quarter
        #pragma unroll
        for (int rep = 0; rep < 4; ++rep) {
            const int u = wid * 4 + rep, g = u >> 2, c = u & 3;
            gload_lds16(Xf + ((xg0 + g) * 16 + srcq * 4 + c) * 512 + lane * 8,
                        nb + u * 512 + lane * 8);
        }
    };

    f32x4 Oa[4][4];
    #pragma unroll
    for (int i = 0; i < 4; ++i)
        #pragma unroll
        for (int j = 0; j < 4; ++j)
            #pragma unroll
            for (int r = 0; r < 4; ++r) Oa[i][j][r] = 0.0f;

    // Z B-frag rolling state (kw-linear: +256 ushorts per 16-k window)
    unsigned zo0 = (unsigned)((zbase >> 4) + wid * 4 + (l32 >> 4)) * 8192u
                   + lane_lo;
    // W base for PV (16x16 B-frags, full-unit lane*8)
    unsigned wmt = (unsigned)(wid * 4) * 131072u
                   + (unsigned)(zbase >> 5) * 512u + (unsigned)lane * 8;

    // ---- prologue: stage q0 -> Xb0, preload zb kw 0,1 ----
    STAGE(0, Xb0);
    frag8 zb[2][2];
    zb[0][0] = *(const frag8*)(Zf + zo0);
    zb[0][1] = *(const frag8*)(Zf + zo0 + 16384u);
    zb[1][0] = *(const frag8*)(Zf + zo0 + 256u);
    zb[1][1] = *(const frag8*)(Zf + zo0 + 16384u + 256u);
    asm volatile("s_waitcnt vmcnt(4)" ::: "memory");   // stage (oldest 4) done
    __builtin_amdgcn_s_barrier();

    #pragma unroll 1
    for (int mt = 0; mt < MT; ++mt) {
        f32x16 S[2][2];
        #pragma unroll
        for (int i = 0; i < 2; ++i)
            #pragma unroll
            for (int j = 0; j < 2; ++j)
                #pragma unroll
                for (int r = 0; r < 16; ++r) S[i][j][r] = 0.0f;

        // ---- QK: 4 quarters x 8 kw; X from LDS ping-pong, Z direct L2 ----
        #pragma unroll
        for (int q = 0; q < 4; ++q) {
            if (q < 3)                STAGE(q + 1, (q & 1) ? Xb0 : Xb1);
            else if (mt + 1 < MT)     STAGE(0, Xb0);     // next mt's q0
            const ushort* Xq = (q & 1) ? Xb1 : Xb0;
            frag8 xa[2][2];
            #pragma unroll
            for (int p = 0; p < 2; ++p) {
                xa[p][0] = *(const frag8*)(Xq + xlane + p * 256);
                xa[p][1] = *(const frag8*)(Xq + xlane + 4096 + p * 256);
            }
            #pragma unroll
            for (int kwl = 0; kwl < 8; ++kwl) {
                const int kw = q * 8 + kwl, s = kwl & 1;
                __builtin_amdgcn_s_setprio(1);
                S[0][0] = __builtin_amdgcn_mfma_f32_32x32x16_bf16(
                    xa[s][0], zb[s][0], S[0][0], 0, 0, 0);
                S[0][1] = __builtin_amdgcn_mfma_f32_32x32x16_bf16(
                    xa[s][0], zb[s][1], S[0][1], 0, 0, 0);
                S[1][0] = __builtin_amdgcn_mfma_f32_32x32x16_bf16(
                    xa[s][1], zb[s][0], S[1][0], 0, 0, 0);
                S[1][1] = __builtin_amdgcn_mfma_f32_32x32x16_bf16(
                    xa[s][1], zb[s][1], S[1][1], 0, 0, 0);
                __builtin_amdgcn_s_setprio(0);
                if (kwl + 2 < 8) {
                    xa[s][0] = *(const frag8*)(Xq + xlane + (kwl + 2) * 256);
                    xa[s][1] = *(const frag8*)(Xq + xlane + 4096 + (kwl + 2) * 256);
                }
                if (kw + 2 < 32) {
                    zb[s][0] = *(const frag8*)(Zf + zo0 + (unsigned)(kw + 2) * 256u);
                    zb[s][1] = *(const frag8*)(Zf + zo0 + 16384u
                                               + (unsigned)(kw + 2) * 256u);
                }
            }
            if (q < 3) __syncthreads();           // quarter swap (vmcnt0+lgkm0)
        }

        // ---- transform S -> packed bf16 P in regs (S dies, frees 48) ----
        const int zc = zbase + mt * 256 + wid * 64 + l32;
        const float zs0 = zsqg[zc], zs1 = zsqg[zc + 32];
        unsigned pp[2][2][8];
        #pragma unroll
        for (int i = 0; i < 2; ++i)
            #pragma unroll
            for (int g = 0; g < 4; ++g) {
                const float4 xq =
                    *(const float4*)(xsqg + row0 + 32 * i + 8 * g + 4 * hb);
                const float xr4[4] = {xq.x, xq.y, xq.z, xq.w};
                #pragma unroll
                for (int j = 0; j < 2; ++j) {
                    const float zz = j ? zs1 : zs0;
                    float e[4];
                    #pragma unroll
                    for (int rr = 0; rr < 4; ++rr) {
                        const float sv = S[i][j][4 * g + rr];
                        float d2 = fmaf(sv, -2.0f, xr4[rr] + zz);
                        d2 = fmaxf(d2, 1e-20f);
                        const float dist = d2 * __frsqrt_rn(d2);   // sqrt
                        e[rr] = __builtin_amdgcn_exp2f(
                            dist * -0.14426950408889634f);         // exp(-d/10)
                    }
                    pp[i][j][2 * g] =
                        (__builtin_bit_cast(unsigned, e[0]) >> 16) |
                        (__builtin_bit_cast(unsigned, e[1]) & 0xFFFF0000u);
                    pp[i][j][2 * g + 1] =
                        (__builtin_bit_cast(unsigned, e[2]) >> 16) |
                        (__builtin_bit_cast(unsigned, e[3]) & 0xFFFF0000u);
                }
            }

        auto WRITE_HALF = [&]() {                 // rows adjacent per pair
            ushort* base = sPh + (wid & 1) * 64 + l32;
            #pragma unroll
            for (int i = 0; i < 2; ++i)
                #pragma unroll
                for (int j = 0; j < 2; ++j)
                    #pragma unroll
                    for (int g = 0; g < 4; ++g) {
                        ushort* w = base + (32 * i + 8 * g + 4 * hb) * LDPH
                                    + 32 * j;
                        const unsigned a = pp[i][j][2 * g];
                        const unsigned b = pp[i][j][2 * g + 1];
                        w[0 * LDPH] = (ushort)a;
                        w[1 * LDPH] = (ushort)(a >> 16);
                        w[2 * LDPH] = (ushort)b;
                        w[3 * LDPH] = (ushort)(b >> 16);
                    }
        };

        const ushort* apw = sPh + l16 * LDPH + quad * 8;
        auto PV = [&](int h) {                    // O += P[:,128h..] W[128h..,:]
            const unsigned wb0 = wmt + (unsigned)(4 * h) * 512u;
            frag8 ap[4], bw[4];
            #pragma unroll
            for (int i = 0; i < 4; ++i)
                ap[i] = *(const frag8*)(apw + i * (16 * LDPH));
            #pragma unroll
            for (int j = 0; j < 4; ++j)
                bw[j] = *(const frag8*)(Wf + wb0 + (unsigned)j * 131072u);
            #pragma unroll
            for (int p = 0; p < 4; ++p) {
                __builtin_amdgcn_s_setprio(1);
                #pragma unroll
                for (int j = 0; j < 4; ++j)
                    #pragma unroll
                    for (int i = 0; i < 4; ++i)
                        Oa[i][j] = __builtin_amdgcn_mfma_f32_16x16x32_bf16(
                            ap[i], bw[j], Oa[i][j], 0, 0, 0);
                __builtin_amdgcn_s_setprio(0);
                if (p < 3) {
                    #pragma unroll
                    for (int i = 0; i < 4; ++i)
                        ap[i] = *(const frag8*)(apw + i * (16 * LDPH)
                                                + (p + 1) * 32);
                    #pragma unroll
                    for (int j = 0; j < 4; ++j)
                        bw[j] = *(const frag8*)(Wf + wb0
                                                + (unsigned)(p + 1) * 512u
                                                + (unsigned)j * 131072u);
                }
            }
        };

        if (wid < 2) WRITE_HALF();                // z 0..128
        __syncthreads();                          // B2a: half0 visible
        PV(0);
        __syncthreads();                          // B3a: half0 reads done
        if (wid >= 2) WRITE_HALF();               // z 128..256
        __syncthreads();                          // B2b: half1 visible
        PV(1);

        // ---- tail: preload next-mt zb; counted-vmcnt mt barrier ----
        if (mt + 1 < MT) {
            zo0 += 131072u; wmt += 4096u;
            zb[0][0] = *(const frag8*)(Zf + zo0);
            zb[0][1] = *(const frag8*)(Zf + zo0 + 16384u);
            zb[1][0] = *(const frag8*)(Zf + zo0 + 256u);
            zb[1][1] = *(const frag8*)(Zf + zo0 + 16384u + 256u);
        }
        asm volatile("s_waitcnt vmcnt(4)" ::: "memory");  // q0 stage long done
        __builtin_amdgcn_s_barrier();
    }

    // ---- epilogue: combine MCH=4 chunks via fp32 atomics (XCD-local) ----
    #pragma unroll
    for (int i = 0; i < 4; ++i) {
        #pragma unroll
        for (int j = 0; j < 4; ++j) {
            const int col = wid * 64 + 16 * j + l16;
            const int xr = row0 + 16 * i + quad * 4;
            #pragma unroll
            for (int rr = 0; rr < 4; ++rr)
                atomicAdd(&O[(size_t)(xr + rr) * Yd + col], Oa[i][j][rr]);
        }
    }
}

// ---- fallback (fp32 VALU fused kernel) if workspace is too small ----
constexpr int FBM = 64, FBN = 64, FBK = 64;
constexpr int FMCH = 4, FMCHUNK = Mm / FMCH, FMSTEPS = FMCHUNK / FBN, FDSTEPS = Dd / FBK;
constexpr int FLDA = FBK + 1, FLDSS = FBN + 1;

__global__ __launch_bounds__(256, 3) void laplace_fused_v1(
    const float* __restrict__ X, const float* __restrict__ Z,
    const float* __restrict__ W, float* __restrict__ O)
{
    __shared__ float sX[FBM * FLDA];
    __shared__ float sZ[FBN * FLDA];
    __shared__ float sS[FBM * FLDSS];
    const int t = threadIdx.x, pr = t >> 4, pc = t & 15, sc4 = pc * 4;
    const int row0 = blockIdx.x * FBM, mbase = blockIdx.y * FMCHUNK;
    float o[4][4][4];
    #pragma unroll
    for (int i = 0; i < 4; ++i)
        for (int yb = 0; yb < 4; ++yb)
            for (int j = 0; j < 4; ++j) o[i][yb][j] = 0.0f;
    for (int ms = 0; ms < FMSTEPS; ++ms) {
        const int zrow0 = mbase + ms * FBN;
        float s[4][4];
        #pragma unroll
        for (int i = 0; i < 4; ++i)
            for (int j = 0; j < 4; ++j) s[i][j] = 0.0f;
        for (int kk = 0; kk < FDSTEPS; ++kk) {
            const int k0 = kk * FBK;
            __syncthreads();
            #pragma unroll
            for (int rep = 0; rep < 4; ++rep) {
                const int r = pr + rep * 16;
                const float4 xv = *reinterpret_cast<const float4*>(X + (size_t)(row0 + r) * Dd + k0 + sc4);
                const float4 zv = *reinterpret_cast<const float4*>(Z + (size_t)(zrow0 + r) * Dd + k0 + sc4);
                float* dx = sX + r * FLDA + sc4;
                dx[0] = xv.x; dx[1] = xv.y; dx[2] = xv.z; dx[3] = xv.w;
                float* dz = sZ + r * FLDA + sc4;
                dz[0] = zv.x; dz[1] = zv.y; dz[2] = zv.z; dz[3] = zv.w;
            }
            __syncthreads();
            #pragma unroll 4
            for (int k = 0; k < FBK; ++k) {
                float xr[4], zc[4];
                #pragma unroll
                for (int i = 0; i < 4; ++i) xr[i] = sX[(pr * 4 + i) * FLDA + k];
                #pragma unroll
                for (int j = 0; j < 4; ++j) zc[j] = sZ[(pc * 4 + j) * FLDA + k];
                #pragma unroll
                for (int i = 0; i < 4; ++i)
                    #pragma unroll
                    for (int j = 0; j < 4; ++j) {
                        const float d = xr[i] - zc[j];
                        s[i][j] = fmaf(d, d, s[i][j]);
                    }
            }
        }
        #pragma unroll
        for (int i = 0; i < 4; ++i)
            for (int j = 0; j < 4; ++j)
                sS[(pr * 4 + i) * FLDSS + sc4 + j] = __expf(-sqrtf(s[i][j]) * 0.1f);
        __syncthreads();
        #pragma unroll 2
        for (int c = 0; c < FBN; ++c) {
            float sv[4];
            #pragma unroll
            for (int i = 0; i < 4; ++i) sv[i] = sS[(pr * 4 + i) * FLDSS + c];
            const float* wrow = W + (size_t)(zrow0 + c) * Yd;
            #pragma unroll
            for (int yb = 0; yb < 4; ++yb) {
                const float4 wv = *reinterpret_cast<const float4*>(wrow + yb * 64 + sc4);
                #pragma unroll
                for (int i = 0; i < 4; ++i) {
                    o[i][yb][0] = fmaf(sv[i], wv.x, o[i][yb][0]);
                    o[i][yb][1] = fmaf(sv[i], wv.y, o[i][yb][1]);
                    o[i][yb][2] = fmaf(sv[i], wv.z, o[i][yb][2]);
                    o[i][yb][3] = fmaf(sv[i], wv.w, o[i][yb][3]);
                }
            }
        }
        __syncthreads();
    }
    #pragma unroll
    for (int i = 0; i < 4; ++i) {
        const size_t rbase = (size_t)(row0 + pr * 4 + i) * Yd;
        #pragma unroll
        for (int yb = 0; yb < 4; ++yb)
            for (int j = 0; j < 4; ++j)
                atomicAdd(O + rbase + yb * 64 + sc4 + j, o[i][yb][j]);
    }
}

extern "C" void kernel_launch(void* const* d_in, const int* in_sizes, int n_in,
                              void* d_out, int out_size, void* d_ws, size_t ws_size,
                              hipStream_t stream) {
    const float* X = (const float*)d_in[0];   // batch   [8192, 512]
    const float* Z = (const float*)d_in[1];   // centers [8192, 512]
    const float* W = (const float*)d_in[2];   // weight  [8192, 256]
    float* O = (float*)d_out;                 // pred    [8192, 256]

    hipMemsetAsync(d_out, 0, (size_t)out_size * sizeof(float), stream);

    if (ws_size < WS_NEED) {
        dim3 grid(Nn / FBM, FMCH);
        laplace_fused_v1<<<grid, dim3(256), 0, stream>>>(X, Z, W, O);
        return;
    }

    char* ws = (char*)d_ws;
    ushort* Xf  = (ushort*)(ws + OFF_XF);
    ushort* Zf  = (ushort*)(ws + OFF_ZF);
    ushort* Wf  = (ushort*)(ws + OFF_WF);
    float*  xsq = (float*)(ws + OFF_XSQ);
    float*  zsq = (float*)(ws + OFF_ZSQ);

    prep_v11<<<dim3(1024 + 256), dim3(256), 0, stream>>>(
        X, Z, W, Xf, Zf, Wf, xsq, zsq);

    laplace_v15<<<dim3(512), dim3(256), 0, stream>>>(
        Xf, Zf, Wf, xsq, zsq, O);
}

// Round 5
// 224.520 us; speedup vs baseline: 2.1539x; 2.1539x over previous
//
#include <hip/hip_runtime.h>

// Laplacian-kernel regression, fused, bf16 MFMA 32x32x16.
//   d2 = ||x||^2 + ||z||^2 - 2 X.Z^T ; P = exp(-sqrt(d2)/10) ; out = P @ W
// R16: v12 base (131us, proven no-spill at launch_bounds(256,2)) + cross-mt
// software pipeline: PV(mt-1) interleaved into QK(mt), one PV zw (4 MFMA)
// per odd kw -> 8 MFMA/kw from two independent streams fills the L2-latency
// stalls that held v12 at MfmaUtil 34%. Enabled by giving sP its own LDS
// (no more R2 time-share): X staged as ping-pong 128-k quarters (2x16 KB,
// v15-verified STAGE math) + sP 33.8 KB = 66,560 B total (same as v12,
// 2 blocks/CU). Occupancy lesson (v13/v14/v15): >2 waves/SIMD cannot host
// the 128-reg 64x64-wave accumulator set; don't try again.
// Arithmetic identical to v12 (same MFMA order) -> same absmax.

using frag8  = __attribute__((ext_vector_type(8)))  short;   // 8 bf16 (4 VGPRs)
using f32x4  = __attribute__((ext_vector_type(4)))  float;
using f32x16 = __attribute__((ext_vector_type(16))) float;   // 32x32 C/D frag

constexpr int Nn = 8192, Mm = 8192, Dd = 512, Yd = 256;
constexpr int BM = 64, BN = 256;
constexpr int MCH = 4, MPER = Mm / MCH, MT = MPER / BN;    // 2048, 8
constexpr int LDP = BN + 8;    // 264 ushort row stride for sP

// Fragment-tile layout (16-row groups, unchanged from prep_v11):
// frag(g, c) = rows [16g,16g+16) x k [32c,32c+32), 512 ushorts at
// (g*KG + c)*512, element (r,k) at ushort lane16*8 + k%8 where
// lane16 = r%16 + 16*((k%32)/8).  Xf/Zf: KG=16 (K=512). Wf: rows=y, KG=256.
// 32x32x16 A/B-frag for lane L (r=L&31, h=L>>5) = one 16B chunk at
// base + kw*256 ushorts (kw = 16-k window).

// workspace layout (bytes)
constexpr size_t OFF_XF  = 0;                               // 8 MB
constexpr size_t OFF_ZF  = OFF_XF + (size_t)Nn * Dd * 2;    // 8 MB
constexpr size_t OFF_WF  = OFF_ZF + (size_t)Mm * Dd * 2;    // 4 MB
constexpr size_t OFF_XSQ = OFF_WF + (size_t)Yd * Mm * 2;
constexpr size_t OFF_ZSQ = OFF_XSQ + (size_t)Nn * 4;
constexpr size_t WS_NEED = OFF_ZSQ + (size_t)Mm * 4;        // ~20.1 MB

__device__ __forceinline__ ushort f2bf(float f) {
    unsigned u = __builtin_bit_cast(unsigned, f);
    u += 0x7FFFu + ((u >> 16) & 1u);          // RNE (prep only)
    return (ushort)(u >> 16);
}

__device__ __forceinline__ void gload_lds16(const ushort* g, ushort* l) {
    __builtin_amdgcn_global_load_lds(
        (const __attribute__((address_space(1))) unsigned int*)(g),
        (__attribute__((address_space(3))) unsigned int*)(l), 16, 0, 0);
}

// ---- prep (LDS-tiled, coalesced) — unchanged from v11 ----
__global__ __launch_bounds__(256) void prep_v11(
    const float* __restrict__ X, const float* __restrict__ Z,
    const float* __restrict__ W, ushort* __restrict__ Xf,
    ushort* __restrict__ Zf, ushort* __restrict__ Wf,
    float* __restrict__ xsq, float* __restrict__ zsq)
{
    __shared__ float tile[8320];                  // 16x517 (X/Z) or 32x260 (W)
    __shared__ float part[256];
    const int t = threadIdx.x, b = blockIdx.x;
    if (b < 1024) {
        const int g = (b < 512) ? b : b - 512;
        const float* src = (b < 512 ? X : Z) + (size_t)g * 16 * Dd;
        ushort* dst = (b < 512 ? Xf : Zf) + (size_t)g * 16 * 512;
        float* nrm = (b < 512 ? xsq : zsq) + g * 16;
        #pragma unroll
        for (int rep = 0; rep < 8; ++rep) {       // 2048 float4, coalesced
            const int idx = rep * 256 + t;
            const int r = idx >> 7, c4 = (idx & 127) * 4;
            const float4 v = *(const float4*)(src + (size_t)r * Dd + c4);
            float* d = tile + r * 517 + c4;
            d[0] = v.x; d[1] = v.y; d[2] = v.z; d[3] = v.w;
        }
        __syncthreads();
        {
            const int r = t & 15, s0 = (t >> 4) * 32;
            float sq = 0.0f;
            #pragma unroll
            for (int k = 0; k < 32; ++k) {
                const float v = tile[r * 517 + s0 + k];
                sq += v * v;
            }
            part[t] = sq;
        }
        __syncthreads();
        if (t < 16) {
            float sq = 0.0f;
            #pragma unroll
            for (int s = 0; s < 16; ++s) sq += part[t + 16 * s];
            nrm[t] = sq;
        }
        #pragma unroll
        for (int rep = 0; rep < 4; ++rep) {       // 1024 uint4 frag writes
            const int idx = rep * 256 + t;
            const int kg = idx >> 6, w = idx & 63;
            const int l16 = w & 15, quad = w >> 4;
            const float* s = tile + l16 * 517 + kg * 32 + quad * 8;
            uint4 pk;
            pk.x = (unsigned)f2bf(s[0]) | ((unsigned)f2bf(s[1]) << 16);
            pk.y = (unsigned)f2bf(s[2]) | ((unsigned)f2bf(s[3]) << 16);
            pk.z = (unsigned)f2bf(s[4]) | ((unsigned)f2bf(s[5]) << 16);
            pk.w = (unsigned)f2bf(s[6]) | ((unsigned)f2bf(s[7]) << 16);
            *(uint4*)(dst + (size_t)kg * 512 + w * 8) = pk;
        }
    } else {
        const int zg = b - 1024;                  // 32-z stripe of W
        const float* src = W + (size_t)zg * 32 * Yd;
        #pragma unroll
        for (int rep = 0; rep < 8; ++rep) {
            const int idx = rep * 256 + t;
            const int r = idx >> 6, c4 = (idx & 63) * 4;
            const float4 v = *(const float4*)(src + (size_t)r * Yd + c4);
            float* d = tile + r * 260 + c4;
            d[0] = v.x; d[1] = v.y; d[2] = v.z; d[3] = v.w;
        }
        __syncthreads();
        #pragma unroll
        for (int rep = 0; rep < 4; ++rep) {
            const int idx = rep * 256 + t;
            const int yg = idx >> 6, w = idx & 63;
            const int l16 = w & 15, quad = w >> 4;
            const int y = yg * 16 + l16;
            ushort rr[8];
            #pragma unroll
            for (int j = 0; j < 8; ++j)
                rr[j] = f2bf(tile[(quad * 8 + j) * 260 + y]);
            uint4 pk;
            pk.x = (unsigned)rr[0] | ((unsigned)rr[1] << 16);
            pk.y = (unsigned)rr[2] | ((unsigned)rr[3] << 16);
            pk.z = (unsigned)rr[4] | ((unsigned)rr[5] << 16);
            pk.w = (unsigned)rr[6] | ((unsigned)rr[7] << 16);
            *(uint4*)(Wf + ((size_t)yg * 256 + zg) * 512 + w * 8) = pk;
        }
    }
}

// ---- main fused kernel (v16): 256 thr, 4 waves 64x64, PV||QK pipeline ----
__global__ __launch_bounds__(256, 2) void laplace_v16(
    const ushort* __restrict__ Xf, const ushort* __restrict__ Zf,
    const ushort* __restrict__ Wf, const float* __restrict__ xsqg,
    const float* __restrict__ zsqg, float* __restrict__ O)
{
    __shared__ ushort sM[8192 * 2 + 16896];       // 66,560 B
    ushort* const Xb0 = sM;                       // X quarter ping (16 KB)
    ushort* const Xb1 = sM + 8192;                // X quarter pong (16 KB)
    ushort* const sP  = sM + 16384;               // P 64x264 (33.8 KB)

    const int t = threadIdx.x, wid = t >> 6, lane = t & 63;
    const int l32 = lane & 31, hb = lane >> 5;

    // XCD-aware swizzle: z-chunk pinned to an XCD pair (grid = 512, 1-D)
    const int bid = blockIdx.x;
    const int xcd = bid & 7;
    const int chunk = xcd >> 1;                   // 0..3
    const int xi = ((xcd & 1) << 6) + (bid >> 3); // 0..127
    const int row0 = xi * BM;
    const int zbase = chunk * MPER;
    const int xg0 = row0 >> 4;

    const int lane_lo = (l32 & 15) * 8 + hb * 128;
    const int xlane = (l32 >> 4) * 2048 + lane_lo;

    auto STAGE = [&](int srcq, ushort* nb) {      // one 64x128k X quarter
        #pragma unroll
        for (int rep = 0; rep < 4; ++rep) {
            const int u = wid * 4 + rep, g = u >> 2, c = u & 3;
            gload_lds16(Xf + ((xg0 + g) * 16 + srcq * 4 + c) * 512 + lane * 8,
                        nb + u * 512 + lane * 8);
        }
    };

    f32x16 Oa[2][2];
    #pragma unroll
    for (int i = 0; i < 2; ++i)
        #pragma unroll
        for (int j = 0; j < 2; ++j)
            #pragma unroll
            for (int r = 0; r < 16; ++r) Oa[i][j][r] = 0.0f;

    unsigned zoQK = (unsigned)((zbase >> 4) + wid * 4 + (l32 >> 4)) * 8192u
                    + (unsigned)lane_lo;
    unsigned zwg = (unsigned)(zbase >> 4);
    const unsigned wyg = (unsigned)(wid * 4 + (l32 >> 4));
    const int paw = l32 * LDP + 8 * hb;           // pa: + i*32*LDP + zw*16

    // ---- prologue: stage q0, preload zb kw0/kw1 ----
    STAGE(0, Xb0);
    frag8 zb[2][2], wb[2][2], pa[2];
    zb[0][0] = *(const frag8*)(Zf + zoQK);
    zb[0][1] = *(const frag8*)(Zf + zoQK + 16384u);
    zb[1][0] = *(const frag8*)(Zf + zoQK + 256u);
    zb[1][1] = *(const frag8*)(Zf + zoQK + 16384u + 256u);
    asm volatile("s_waitcnt vmcnt(4)" ::: "memory");   // stage (oldest 4) done
    __builtin_amdgcn_s_barrier();

    unsigned woPV = 0;

    #pragma unroll 1
    for (int mt = 0; mt < MT; ++mt) {
        const bool doPV = (mt > 0);
        f32x16 S[2][2];
        #pragma unroll
        for (int i = 0; i < 2; ++i)
            #pragma unroll
            for (int j = 0; j < 2; ++j)
                #pragma unroll
                for (int r = 0; r < 16; ++r) S[i][j][r] = 0.0f;

        // ---- QK (32 kw) with PV(mt-1) interleaved at odd kw ----
        #pragma unroll
        for (int q = 0; q < 4; ++q) {
            if (q < 3)                STAGE(q + 1, (q & 1) ? Xb0 : Xb1);
            else if (mt + 1 < MT)     STAGE(0, Xb0);       // next mt's q0
            const ushort* Xq = (q & 1) ? Xb1 : Xb0;
            frag8 xa[2][2];
            #pragma unroll
            for (int p = 0; p < 2; ++p) {
                xa[p][0] = *(const frag8*)(Xq + xlane + p * 256);
                xa[p][1] = *(const frag8*)(Xq + xlane + 4096 + p * 256);
            }
            #pragma unroll
            for (int kwl = 0; kwl < 8; ++kwl) {
                const int kw = q * 8 + kwl, s = kwl & 1;
                __builtin_amdgcn_s_setprio(1);
                S[0][0] = __builtin_amdgcn_mfma_f32_32x32x16_bf16(
                    xa[s][0], zb[s][0], S[0][0], 0, 0, 0);
                S[0][1] = __builtin_amdgcn_mfma_f32_32x32x16_bf16(
                    xa[s][0], zb[s][1], S[0][1], 0, 0, 0);
                S[1][0] = __builtin_amdgcn_mfma_f32_32x32x16_bf16(
                    xa[s][1], zb[s][0], S[1][0], 0, 0, 0);
                S[1][1] = __builtin_amdgcn_mfma_f32_32x32x16_bf16(
                    xa[s][1], zb[s][1], S[1][1], 0, 0, 0);
                __builtin_amdgcn_s_setprio(0);
                if (kw + 2 < 32) {
                    zb[s][0] = *(const frag8*)(Zf + zoQK
                                               + (unsigned)(kw + 2) * 256u);
                    zb[s][1] = *(const frag8*)(Zf + zoQK + 16384u
                                               + (unsigned)(kw + 2) * 256u);
                }
                if (kwl + 2 < 8) {
                    xa[s][0] = *(const frag8*)(Xq + xlane + (kwl + 2) * 256);
                    xa[s][1] = *(const frag8*)(Xq + xlane + 4096
                                               + (kwl + 2) * 256);
                }
                if ((kw & 1) && doPV) {           // PV(mt-1), zw = kw>>1
                    const int zw = kw >> 1, s2 = zw & 1;
                    __builtin_amdgcn_s_setprio(1);
                    Oa[0][0] = __builtin_amdgcn_mfma_f32_32x32x16_bf16(
                        pa[0], wb[s2][0], Oa[0][0], 0, 0, 0);
                    Oa[0][1] = __builtin_amdgcn_mfma_f32_32x32x16_bf16(
                        pa[0], wb[s2][1], Oa[0][1], 0, 0, 0);
                    Oa[1][0] = __builtin_amdgcn_mfma_f32_32x32x16_bf16(
                        pa[1], wb[s2][0], Oa[1][0], 0, 0, 0);
                    Oa[1][1] = __builtin_amdgcn_mfma_f32_32x32x16_bf16(
                        pa[1], wb[s2][1], Oa[1][1], 0, 0, 0);
                    __builtin_amdgcn_s_setprio(0);
                    if (zw + 1 < 16) {            // pa depth-1 (LDS, fast)
                        pa[0] = *(const frag8*)(sP + paw + (zw + 1) * 16);
                        pa[1] = *(const frag8*)(sP + paw + 32 * LDP
                                                + (zw + 1) * 16);
                    }
                    if (zw + 2 < 16) {            // wb depth-2 (L2)
                        wb[s2][0] = *(const frag8*)(Wf + woPV
                                        + (unsigned)(zw + 2) * 256u);
                        wb[s2][1] = *(const frag8*)(Wf + woPV + 262144u
                                        + (unsigned)(zw + 2) * 256u);
                    }
                }
            }
            __syncthreads();   // quarter swap; q=3: also PV readers done
        }

        // ---- transform S -> sP (C/D: col=l32, row=(r&3)+8*(r>>2)+4*hb) ----
        {
            const int zc = zbase + mt * 256 + wid * 64 + l32;
            const float zs0 = zsqg[zc], zs1 = zsqg[zc + 32];
            #pragma unroll
            for (int i = 0; i < 2; ++i) {
                #pragma unroll
                for (int g = 0; g < 4; ++g) {
                    const float4 xq = *(const float4*)(
                        xsqg + row0 + 32 * i + 8 * g + 4 * hb);
                    const float xr4[4] = {xq.x, xq.y, xq.z, xq.w};
                    #pragma unroll
                    for (int j = 0; j < 2; ++j) {
                        const float zz = j ? zs1 : zs0;
                        #pragma unroll
                        for (int rr = 0; rr < 4; ++rr) {
                            const float sv = S[i][j][4 * g + rr];
                            float d2 = fmaf(sv, -2.0f, xr4[rr] + zz);
                            d2 = fmaxf(d2, 1e-20f);
                            const float dist = d2 * __frsqrt_rn(d2);   // sqrt
                            const float e = __builtin_amdgcn_exp2f(
                                dist * -0.14426950408889634f);  // exp(-d/10)
                            sP[(32 * i + rr + 8 * g + 4 * hb) * LDP
                               + wid * 64 + 32 * j + l32] =
                                (ushort)(__builtin_bit_cast(unsigned, e) >> 16);
                        }
                    }
                }
            }
        }
        woPV = wyg * 131072u + zwg * 256u + (unsigned)lane_lo;  // W of THIS mt
        __syncthreads();   // sP visible to all waves

        // ---- tail: advance QK stream; preload zb/pa/wb for next round ----
        if (mt + 1 < MT) {
            zoQK += 131072u;
            zb[0][0] = *(const frag8*)(Zf + zoQK);
            zb[0][1] = *(const frag8*)(Zf + zoQK + 16384u);
            zb[1][0] = *(const frag8*)(Zf + zoQK + 256u);
            zb[1][1] = *(const frag8*)(Zf + zoQK + 16384u + 256u);
        }
        zwg += 16u;
        pa[0] = *(const frag8*)(sP + paw);                  // zw0
        pa[1] = *(const frag8*)(sP + paw + 32 * LDP);
        wb[0][0] = *(const frag8*)(Wf + woPV);
        wb[0][1] = *(const frag8*)(Wf + woPV + 262144u);
        wb[1][0] = *(const frag8*)(Wf + woPV + 256u);
        wb[1][1] = *(const frag8*)(Wf + woPV + 262144u + 256u);
    }

    // ---- epilogue: PV for the last mt (no QK to hide under) ----
    #pragma unroll
    for (int zw = 0; zw < 16; ++zw) {
        const int s2 = zw & 1;
        __builtin_amdgcn_s_setprio(1);
        Oa[0][0] = __builtin_amdgcn_mfma_f32_32x32x16_bf16(
            pa[0], wb[s2][0], Oa[0][0], 0, 0, 0);
        Oa[0][1] = __builtin_amdgcn_mfma_f32_32x32x16_bf16(
            pa[0], wb[s2][1], Oa[0][1], 0, 0, 0);
        Oa[1][0] = __builtin_amdgcn_mfma_f32_32x32x16_bf16(
            pa[1], wb[s2][0], Oa[1][0], 0, 0, 0);
        Oa[1][1] = __builtin_amdgcn_mfma_f32_32x32x16_bf16(
            pa[1], wb[s2][1], Oa[1][1], 0, 0, 0);
        __builtin_amdgcn_s_setprio(0);
        if (zw + 1 < 16) {
            pa[0] = *(const frag8*)(sP + paw + (zw + 1) * 16);
            pa[1] = *(const frag8*)(sP + paw + 32 * LDP + (zw + 1) * 16);
        }
        if (zw + 2 < 16) {
            wb[s2][0] = *(const frag8*)(Wf + woPV + (unsigned)(zw + 2) * 256u);
            wb[s2][1] = *(const frag8*)(Wf + woPV + 262144u
                                        + (unsigned)(zw + 2) * 256u);
        }
    }

    // ---- combine MCH=4 chunks via fp32 atomics (XCD-local) ----
    #pragma unroll
    for (int j = 0; j < 2; ++j) {
        const int yg = wid * 64 + 32 * j + l32;
        #pragma unroll
        for (int r = 0; r < 16; ++r) {
            const float ov = j ? Oa[0][1][r] : Oa[0][0][r];
            const int xg = row0 + (r & 3) + 8 * (r >> 2) + 4 * hb;
            atomicAdd(&O[(size_t)xg * Yd + yg], ov);
        }
        #pragma unroll
        for (int r = 0; r < 16; ++r) {
            const float ov = j ? Oa[1][1][r] : Oa[1][0][r];
            const int xg = row0 + 32 + (r & 3) + 8 * (r >> 2) + 4 * hb;
            atomicAdd(&O[(size_t)xg * Yd + yg], ov);
        }
    }
}

// ---- fallback (fp32 VALU fused kernel) if workspace is too small ----
constexpr int FBM = 64, FBN = 64, FBK = 64;
constexpr int FMCH = 4, FMCHUNK = Mm / FMCH, FMSTEPS = FMCHUNK / FBN, FDSTEPS = Dd / FBK;
constexpr int FLDA = FBK + 1, FLDSS = FBN + 1;

__global__ __launch_bounds__(256, 3) void laplace_fused_v1(
    const float* __restrict__ X, const float* __restrict__ Z,
    const float* __restrict__ W, float* __restrict__ O)
{
    __shared__ float sX[FBM * FLDA];
    __shared__ float sZ[FBN * FLDA];
    __shared__ float sS[FBM * FLDSS];
    const int t = threadIdx.x, pr = t >> 4, pc = t & 15, sc4 = pc * 4;
    const int row0 = blockIdx.x * FBM, mbase = blockIdx.y * FMCHUNK;
    float o[4][4][4];
    #pragma unroll
    for (int i = 0; i < 4; ++i)
        for (int yb = 0; yb < 4; ++yb)
            for (int j = 0; j < 4; ++j) o[i][yb][j] = 0.0f;
    for (int ms = 0; ms < FMSTEPS; ++ms) {
        const int zrow0 = mbase + ms * FBN;
        float s[4][4];
        #pragma unroll
        for (int i = 0; i < 4; ++i)
            for (int j = 0; j < 4; ++j) s[i][j] = 0.0f;
        for (int kk = 0; kk < FDSTEPS; ++kk) {
            const int k0 = kk * FBK;
            __syncthreads();
            #pragma unroll
            for (int rep = 0; rep < 4; ++rep) {
                const int r = pr + rep * 16;
                const float4 xv = *reinterpret_cast<const float4*>(X + (size_t)(row0 + r) * Dd + k0 + sc4);
                const float4 zv = *reinterpret_cast<const float4*>(Z + (size_t)(zrow0 + r) * Dd + k0 + sc4);
                float* dx = sX + r * FLDA + sc4;
                dx[0] = xv.x; dx[1] = xv.y; dx[2] = xv.z; dx[3] = xv.w;
                float* dz = sZ + r * FLDA + sc4;
                dz[0] = zv.x; dz[1] = zv.y; dz[2] = zv.z; dz[3] = zv.w;
            }
            __syncthreads();
            #pragma unroll 4
            for (int k = 0; k < FBK; ++k) {
                float xr[4], zc[4];
                #pragma unroll
                for (int i = 0; i < 4; ++i) xr[i] = sX[(pr * 4 + i) * FLDA + k];
                #pragma unroll
                for (int j = 0; j < 4; ++j) zc[j] = sZ[(pc * 4 + j) * FLDA + k];
                #pragma unroll
                for (int i = 0; i < 4; ++i)
                    #pragma unroll
                    for (int j = 0; j < 4; ++j) {
                        const float d = xr[i] - zc[j];
                        s[i][j] = fmaf(d, d, s[i][j]);
                    }
            }
        }
        #pragma unroll
        for (int i = 0; i < 4; ++i)
            for (int j = 0; j < 4; ++j)
                sS[(pr * 4 + i) * FLDSS + sc4 + j] = __expf(-sqrtf(s[i][j]) * 0.1f);
        __syncthreads();
        #pragma unroll 2
        for (int c = 0; c < FBN; ++c) {
            float sv[4];
            #pragma unroll
            for (int i = 0; i < 4; ++i) sv[i] = sS[(pr * 4 + i) * FLDSS + c];
            const float* wrow = W + (size_t)(zrow0 + c) * Yd;
            #pragma unroll
            for (int yb = 0; yb < 4; ++yb) {
                const float4 wv = *reinterpret_cast<const float4*>(wrow + yb * 64 + sc4);
                #pragma unroll
                for (int i = 0; i < 4; ++i) {
                    o[i][yb][0] = fmaf(sv[i], wv.x, o[i][yb][0]);
                    o[i][yb][1] = fmaf(sv[i], wv.y, o[i][yb][1]);
                    o[i][yb][2] = fmaf(sv[i], wv.z, o[i][yb][2]);
                    o[i][yb][3] = fmaf(sv[i], wv.w, o[i][yb][3]);
                }
            }
        }
        __syncthreads();
    }
    #pragma unroll
    for (int i = 0; i < 4; ++i) {
        const size_t rbase = (size_t)(row0 + pr * 4 + i) * Yd;
        #pragma unroll
        for (int yb = 0; yb < 4; ++yb)
            for (int j = 0; j < 4; ++j)
                atomicAdd(O + rbase + yb * 64 + sc4 + j, o[i][yb][j]);
    }
}

extern "C" void kernel_launch(void* const* d_in, const int* in_sizes, int n_in,
                              void* d_out, int out_size, void* d_ws, size_t ws_size,
                              hipStream_t stream) {
    const float* X = (const float*)d_in[0];   // batch   [8192, 512]
    const float* Z = (const float*)d_in[1];   // centers [8192, 512]
    const float* W = (const float*)d_in[2];   // weight  [8192, 256]
    float* O = (float*)d_out;                 // pred    [8192, 256]

    hipMemsetAsync(d_out, 0, (size_t)out_size * sizeof(float), stream);

    if (ws_size < WS_NEED) {
        dim3 grid(Nn / FBM, FMCH);
        laplace_fused_v1<<<grid, dim3(256), 0, stream>>>(X, Z, W, O);
        return;
    }

    char* ws = (char*)d_ws;
    ushort* Xf  = (ushort*)(ws + OFF_XF);
    ushort* Zf  = (ushort*)(ws + OFF_ZF);
    ushort* Wf  = (ushort*)(ws + OFF_WF);
    float*  xsq = (float*)(ws + OFF_XSQ);
    float*  zsq = (float*)(ws + OFF_ZSQ);

    prep_v11<<<dim3(1024 + 256), dim3(256), 0, stream>>>(
        X, Z, W, Xf, Zf, Wf, xsq, zsq);

    laplace_v16<<<dim3(512), dim3(256), 0, stream>>>(
        Xf, Zf, Wf, xsq, zsq, O);
}

// Round 6
// 216.862 us; speedup vs baseline: 2.2300x; 1.0353x over previous
//
#include <hip/hip_runtime.h>

// Laplacian-kernel regression, fused, bf16 MFMA 16x16x32.
//   d2 = ||x||^2 + ||z||^2 - 2 X.Z^T ; P = exp(-sqrt(d2)/10) ; out = P @ W
// R17: v12 base (131us, best known) + surgical latency fixes, NO
// restructure (v13-v16 all lost: spill / reuse-loss / traffic blowup):
//  1. X staging via global_load_lds (was VGPR round-trip copy).
//  2. next-mt h0 stage issued right after B1 (sXh dead B1 -> next mt)
//     -> latency hides under transform+PV; only h1 stage exposed.
//  3. rolling depth-2 dbuf for L2 streams: bz[2][4] (QK), bw[2][4] (PV);
//     h-entry Z preloads issued BEFORE the stage barrier (latency merges
//     with stage drain).
// Same LDS layout (sXh 32KB + sP 33.8KB = 66,560B, 2 blocks/CU), same
// barriers/mt (5), same grid (128,4), same MFMA order -> same absmax.

using frag8  = __attribute__((ext_vector_type(8)))  short;   // 8 bf16 (4 VGPRs)
using f32x4  = __attribute__((ext_vector_type(4)))  float;   // 16x16 C/D frag

constexpr int Nn = 8192, Mm = 8192, Dd = 512, Yd = 256;
constexpr int BM = 64, BN = 256;
constexpr int MCH = 4, MPER = Mm / MCH, MT = MPER / BN;    // 2048, 8
constexpr int LDP = BN + 8;    // 264 ushort rows (528 B, 16B-aligned)

// Fragment-tile layout: frag(g, c) = rows [16g,16g+16) x k [32c,32c+32),
// 512 ushorts at (g*KG + c)*512, element (r,k) at ushort lane*8 + k%8 where
// lane = r%16 + 16*((k%32)/8).  Xf/Zf: KG=16 (K=512). Wf: rows=y, KG=256.

// workspace layout (bytes)
constexpr size_t OFF_XF  = 0;                               // 8 MB
constexpr size_t OFF_ZF  = OFF_XF + (size_t)Nn * Dd * 2;    // 8 MB
constexpr size_t OFF_WF  = OFF_ZF + (size_t)Mm * Dd * 2;    // 4 MB
constexpr size_t OFF_XSQ = OFF_WF + (size_t)Yd * Mm * 2;
constexpr size_t OFF_ZSQ = OFF_XSQ + (size_t)Nn * 4;
constexpr size_t WS_NEED = OFF_ZSQ + (size_t)Mm * 4;        // ~20.1 MB

__device__ __forceinline__ ushort f2bf(float f) {
    unsigned u = __builtin_bit_cast(unsigned, f);
    u += 0x7FFFu + ((u >> 16) & 1u);          // RNE (prep only)
    return (ushort)(u >> 16);
}

__device__ __forceinline__ void gload_lds16(const ushort* g, ushort* l) {
    __builtin_amdgcn_global_load_lds(
        (const __attribute__((address_space(1))) unsigned int*)(g),
        (__attribute__((address_space(3))) unsigned int*)(l), 16, 0, 0);
}

// ---- prep (LDS-tiled, coalesced) — unchanged from v11 ----
__global__ __launch_bounds__(256) void prep_v11(
    const float* __restrict__ X, const float* __restrict__ Z,
    const float* __restrict__ W, ushort* __restrict__ Xf,
    ushort* __restrict__ Zf, ushort* __restrict__ Wf,
    float* __restrict__ xsq, float* __restrict__ zsq)
{
    __shared__ float tile[8320];                  // 16x517 (X/Z) or 32x260 (W)
    __shared__ float part[256];
    const int t = threadIdx.x, b = blockIdx.x;
    if (b < 1024) {
        const int g = (b < 512) ? b : b - 512;
        const float* src = (b < 512 ? X : Z) + (size_t)g * 16 * Dd;
        ushort* dst = (b < 512 ? Xf : Zf) + (size_t)g * 16 * 512;
        float* nrm = (b < 512 ? xsq : zsq) + g * 16;
        #pragma unroll
        for (int rep = 0; rep < 8; ++rep) {       // 2048 float4, coalesced
            const int idx = rep * 256 + t;
            const int r = idx >> 7, c4 = (idx & 127) * 4;
            const float4 v = *(const float4*)(src + (size_t)r * Dd + c4);
            float* d = tile + r * 517 + c4;
            d[0] = v.x; d[1] = v.y; d[2] = v.z; d[3] = v.w;
        }
        __syncthreads();
        {
            const int r = t & 15, s0 = (t >> 4) * 32;
            float sq = 0.0f;
            #pragma unroll
            for (int k = 0; k < 32; ++k) {
                const float v = tile[r * 517 + s0 + k];
                sq += v * v;
            }
            part[t] = sq;
        }
        __syncthreads();
        if (t < 16) {
            float sq = 0.0f;
            #pragma unroll
            for (int s = 0; s < 16; ++s) sq += part[t + 16 * s];
            nrm[t] = sq;
        }
        #pragma unroll
        for (int rep = 0; rep < 4; ++rep) {       // 1024 uint4 frag writes
            const int idx = rep * 256 + t;
            const int kg = idx >> 6, w = idx & 63;
            const int l16 = w & 15, quad = w >> 4;
            const float* s = tile + l16 * 517 + kg * 32 + quad * 8;
            uint4 pk;
            pk.x = (unsigned)f2bf(s[0]) | ((unsigned)f2bf(s[1]) << 16);
            pk.y = (unsigned)f2bf(s[2]) | ((unsigned)f2bf(s[3]) << 16);
            pk.z = (unsigned)f2bf(s[4]) | ((unsigned)f2bf(s[5]) << 16);
            pk.w = (unsigned)f2bf(s[6]) | ((unsigned)f2bf(s[7]) << 16);
            *(uint4*)(dst + (size_t)kg * 512 + w * 8) = pk;
        }
    } else {
        const int zg = b - 1024;                  // 32-z stripe of W
        const float* src = W + (size_t)zg * 32 * Yd;
        #pragma unroll
        for (int rep = 0; rep < 8; ++rep) {
            const int idx = rep * 256 + t;
            const int r = idx >> 6, c4 = (idx & 63) * 4;
            const float4 v = *(const float4*)(src + (size_t)r * Yd + c4);
            float* d = tile + r * 260 + c4;
            d[0] = v.x; d[1] = v.y; d[2] = v.z; d[3] = v.w;
        }
        __syncthreads();
        #pragma unroll
        for (int rep = 0; rep < 4; ++rep) {
            const int idx = rep * 256 + t;
            const int yg = idx >> 6, w = idx & 63;
            const int l16 = w & 15, quad = w >> 4;
            const int y = yg * 16 + l16;
            ushort rr[8];
            #pragma unroll
            for (int j = 0; j < 8; ++j)
                rr[j] = f2bf(tile[(quad * 8 + j) * 260 + y]);
            uint4 pk;
            pk.x = (unsigned)rr[0] | ((unsigned)rr[1] << 16);
            pk.y = (unsigned)rr[2] | ((unsigned)rr[3] << 16);
            pk.z = (unsigned)rr[4] | ((unsigned)rr[5] << 16);
            pk.w = (unsigned)rr[6] | ((unsigned)rr[7] << 16);
            *(uint4*)(Wf + ((size_t)yg * 256 + zg) * 512 + w * 8) = pk;
        }
    }
}

// ---- main fused kernel (v17): v12 structure + gload_lds + rolling dbuf ----
__global__ __launch_bounds__(256, 2) void laplace_v17(
    const ushort* __restrict__ Xf, const ushort* __restrict__ Zf,
    const ushort* __restrict__ Wf, const float* __restrict__ xsqg,
    const float* __restrict__ zsqg, float* __restrict__ O)
{
    __shared__ ushort sXh[32 * 512];              // 32 KB: X K-half (32 units)
    __shared__ ushort sP[BM * LDP];               // 33.8 KB
    const int t = threadIdx.x, wid = t >> 6, lane = t & 63;
    const int l16 = lane & 15, quad = lane >> 4;
    const int row0  = blockIdx.x * BM;            // XCD = blockIdx.x % 8
    const int zbase = blockIdx.y * MPER;
    const int xg0 = row0 >> 4;                    // X 16-row-group base

    float xs[4][4];
    #pragma unroll
    for (int i = 0; i < 4; ++i)
        #pragma unroll
        for (int r = 0; r < 4; ++r)
            xs[i][r] = xsqg[row0 + 16 * i + quad * 4 + r];

    f32x4 Oa[4][4];
    #pragma unroll
    for (int i = 0; i < 4; ++i)
        #pragma unroll
        for (int j = 0; j < 4; ++j)
            #pragma unroll
            for (int r = 0; r < 4; ++r) Oa[i][j][r] = 0.0f;

    // wave-contiguous staging pointers: wave wid stages row-group (xg0+wid),
    // 8 k-units per half (identical byte mapping to v12)
    const ushort* xsrc = Xf + ((size_t)(xg0 + wid) * 16) * 512 + lane * 8;
    ushort* xdst = sXh + wid * 8 * 512 + lane * 8;

    // ---- prologue: async-stage h0 of mt 0 ----
    #pragma unroll
    for (int c = 0; c < 8; ++c)
        gload_lds16(xsrc + c * 512, xdst + c * 512);

    #pragma unroll 1
    for (int mt = 0; mt < MT; ++mt) {
        const int zg0 = (zbase >> 4) + mt * 16;
        float zs4[4];
        #pragma unroll
        for (int j = 0; j < 4; ++j)
            zs4[j] = zsqg[zbase + mt * 256 + wid * 64 + 16 * j + l16];

        f32x4 S[4][4];
        #pragma unroll
        for (int i = 0; i < 4; ++i)
            #pragma unroll
            for (int j = 0; j < 4; ++j)
                #pragma unroll
                for (int r = 0; r < 4; ++r) S[i][j][r] = 0.0f;

        const unsigned zo0 = (unsigned)(zg0 + wid * 4) * 8192u + lane * 8;

        // ---- QK in two K-halves; X from LDS (4x reuse), Z rolling dbuf ----
        frag8 bz[2][4];
        #pragma unroll
        for (int h = 0; h < 2; ++h) {
            const unsigned zoh = zo0 + (unsigned)h * 4096u;
            // preload bz kk0/kk1 BEFORE the stage barrier: latency merges
            // with the stage drain.
            #pragma unroll
            for (int j = 0; j < 4; ++j) {
                bz[0][j] = *(const frag8*)(Zf + zoh + j * 8192u);
                bz[1][j] = *(const frag8*)(Zf + zoh + 512u + j * 8192u);
            }
            if (h == 1) {
                // stage h1 into sXh (reads of h0 finished at h0-end barrier)
                #pragma unroll
                for (int c = 0; c < 8; ++c)
                    gload_lds16(xsrc + (8 + c) * 512, xdst + c * 512);
            }
            asm volatile("s_waitcnt vmcnt(0)" ::: "memory");
            __syncthreads();                      // sXh half ready
            #pragma unroll
            for (int kk = 0; kk < 8; ++kk) {
                const int cb = kk & 1;
                frag8 a[4];
                #pragma unroll
                for (int i = 0; i < 4; ++i)
                    a[i] = *(const frag8*)(sXh + (i * 8 + kk) * 512 + lane * 8);
                #pragma unroll
                for (int i = 0; i < 4; ++i)
                    #pragma unroll
                    for (int j = 0; j < 4; ++j)
                        S[i][j] = __builtin_amdgcn_mfma_f32_16x16x32_bf16(
                            a[i], bz[cb][j], S[i][j], 0, 0, 0);
                if (kk + 2 < 8) {                 // depth-2 rolling refill
                    #pragma unroll
                    for (int j = 0; j < 4; ++j)
                        bz[cb][j] = *(const frag8*)(
                            Zf + zoh + (unsigned)(kk + 2) * 512u + j * 8192u);
                }
            }
            __syncthreads();                      // half reads done
        }
        // here: B1 equivalent passed (2nd __syncthreads above) — sXh free

        // ---- async-stage next mt's h0 (hides under transform + PV) ----
        if (mt + 1 < MT) {
            #pragma unroll
            for (int c = 0; c < 8; ++c)
                gload_lds16(xsrc + c * 512, xdst + c * 512);
        }
        // preload PV wb pv0/pv1 (L2, no sP dep) — hides under transform
        const unsigned wo0 = (unsigned)(wid * 4) * 131072u +
                             (unsigned)((zbase >> 5) + mt * 8) * 512u + lane * 8;
        frag8 bw[2][4];
        #pragma unroll
        for (int j = 0; j < 4; ++j) {
            bw[0][j] = *(const frag8*)(Wf + wo0 + j * 131072u);
            bw[1][j] = *(const frag8*)(Wf + wo0 + 512u + j * 131072u);
        }

        // ---- transform -> sP (C/D: col=l16, row=quad*4+r) ----
        #pragma unroll
        for (int i = 0; i < 4; ++i) {
            const int xl = 16 * i + quad * 4;
            #pragma unroll
            for (int j = 0; j < 4; ++j) {
                const int col = wid * 64 + 16 * j + l16;
                const float zz = zs4[j];
                #pragma unroll
                for (int r = 0; r < 4; ++r) {
                    const float xpz = xs[i][r] + zz;
                    float d2 = fmaf(S[i][j][r], -2.0f, xpz);
                    d2 = fmaxf(d2, 1e-20f);
                    const float dist = d2 * __frsqrt_rn(d2);     // sqrt(d2)
                    const float e = __builtin_amdgcn_exp2f(
                        dist * -0.14426950408889634f);           // exp(-dist/10)
                    sP[(xl + r) * LDP + col] =
                        (ushort)(__builtin_bit_cast(unsigned, e) >> 16);
                }
            }
        }
        __syncthreads();                          // sP visible (drains stage)

        // ---- PV: O += P[64x256].W[256x256]; A from sP, W rolling dbuf ----
        #pragma unroll
        for (int pv = 0; pv < 8; ++pv) {
            const int cb = pv & 1;
            frag8 ap[4];
            #pragma unroll
            for (int i = 0; i < 4; ++i)
                ap[i] = *(const frag8*)(
                    sP + (16 * i + l16) * LDP + pv * 32 + quad * 8);
            #pragma unroll
            for (int j = 0; j < 4; ++j)
                #pragma unroll
                for (int i = 0; i < 4; ++i)
                    Oa[i][j] = __builtin_amdgcn_mfma_f32_16x16x32_bf16(
                        ap[i], bw[cb][j], Oa[i][j], 0, 0, 0);
            if (pv + 2 < 8) {                     // depth-2 rolling refill
                #pragma unroll
                for (int j = 0; j < 4; ++j)
                    bw[cb][j] = *(const frag8*)(
                        Wf + wo0 + (unsigned)(pv + 2) * 512u + j * 131072u);
            }
        }
        // next mt's h0-ready barrier implies sP reads done (sP reused only
        // after next transform's own barrier) — matches v12's reasoning.
    }

    // ---- epilogue: combine MCH=4 chunks via fp32 atomics (XCD-local) ----
    #pragma unroll
    for (int i = 0; i < 4; ++i) {
        const int xr = row0 + 16 * i + quad * 4;
        #pragma unroll
        for (int j = 0; j < 4; ++j) {
            const int col = wid * 64 + 16 * j + l16;
            #pragma unroll
            for (int r = 0; r < 4; ++r)
                atomicAdd(&O[(size_t)(xr + r) * Yd + col], Oa[i][j][r]);
        }
    }
}

// ---- fallback (fp32 VALU fused kernel) if workspace is too small ----
constexpr int FBM = 64, FBN = 64, FBK = 64;
constexpr int FMCH = 4, FMCHUNK = Mm / FMCH, FMSTEPS = FMCHUNK / FBN, FDSTEPS = Dd / FBK;
constexpr int FLDA = FBK + 1, FLDSS = FBN + 1;

__global__ __launch_bounds__(256, 3) void laplace_fused_v1(
    const float* __restrict__ X, const float* __restrict__ Z,
    const float* __restrict__ W, float* __restrict__ O)
{
    __shared__ float sX[FBM * FLDA];
    __shared__ float sZ[FBN * FLDA];
    __shared__ float sS[FBM * FLDSS];
    const int t = threadIdx.x, pr = t >> 4, pc = t & 15, sc4 = pc * 4;
    const int row0 = blockIdx.x * FBM, mbase = blockIdx.y * FMCHUNK;
    float o[4][4][4];
    #pragma unroll
    for (int i = 0; i < 4; ++i)
        for (int yb = 0; yb < 4; ++yb)
            for (int j = 0; j < 4; ++j) o[i][yb][j] = 0.0f;
    for (int ms = 0; ms < FMSTEPS; ++ms) {
        const int zrow0 = mbase + ms * FBN;
        float s[4][4];
        #pragma unroll
        for (int i = 0; i < 4; ++i)
            for (int j = 0; j < 4; ++j) s[i][j] = 0.0f;
        for (int kk = 0; kk < FDSTEPS; ++kk) {
            const int k0 = kk * FBK;
            __syncthreads();
            #pragma unroll
            for (int rep = 0; rep < 4; ++rep) {
                const int r = pr + rep * 16;
                const float4 xv = *reinterpret_cast<const float4*>(X + (size_t)(row0 + r) * Dd + k0 + sc4);
                const float4 zv = *reinterpret_cast<const float4*>(Z + (size_t)(zrow0 + r) * Dd + k0 + sc4);
                float* dx = sX + r * FLDA + sc4;
                dx[0] = xv.x; dx[1] = xv.y; dx[2] = xv.z; dx[3] = xv.w;
                float* dz = sZ + r * FLDA + sc4;
                dz[0] = zv.x; dz[1] = zv.y; dz[2] = zv.z; dz[3] = zv.w;
            }
            __syncthreads();
            #pragma unroll 4
            for (int k = 0; k < FBK; ++k) {
                float xr[4], zc[4];
                #pragma unroll
                for (int i = 0; i < 4; ++i) xr[i] = sX[(pr * 4 + i) * FLDA + k];
                #pragma unroll
                for (int j = 0; j < 4; ++j) zc[j] = sZ[(pc * 4 + j) * FLDA + k];
                #pragma unroll
                for (int i = 0; i < 4; ++i)
                    #pragma unroll
                    for (int j = 0; j < 4; ++j) {
                        const float d = xr[i] - zc[j];
                        s[i][j] = fmaf(d, d, s[i][j]);
                    }
            }
        }
        #pragma unroll
        for (int i = 0; i < 4; ++i)
            for (int j = 0; j < 4; ++j)
                sS[(pr * 4 + i) * FLDSS + sc4 + j] = __expf(-sqrtf(s[i][j]) * 0.1f);
        __syncthreads();
        #pragma unroll 2
        for (int c = 0; c < FBN; ++c) {
            float sv[4];
            #pragma unroll
            for (int i = 0; i < 4; ++i) sv[i] = sS[(pr * 4 + i) * FLDSS + c];
            const float* wrow = W + (size_t)(zrow0 + c) * Yd;
            #pragma unroll
            for (int yb = 0; yb < 4; ++yb) {
                const float4 wv = *reinterpret_cast<const float4*>(wrow + yb * 64 + sc4);
                #pragma unroll
                for (int i = 0; i < 4; ++i) {
                    o[i][yb][0] = fmaf(sv[i], wv.x, o[i][yb][0]);
                    o[i][yb][1] = fmaf(sv[i], wv.y, o[i][yb][1]);
                    o[i][yb][2] = fmaf(sv[i], wv.z, o[i][yb][2]);
                    o[i][yb][3] = fmaf(sv[i], wv.w, o[i][yb][3]);
                }
            }
        }
        __syncthreads();
    }
    #pragma unroll
    for (int i = 0; i < 4; ++i) {
        const size_t rbase = (size_t)(row0 + pr * 4 + i) * Yd;
        #pragma unroll
        for (int yb = 0; yb < 4; ++yb)
            for (int j = 0; j < 4; ++j)
                atomicAdd(O + rbase + yb * 64 + sc4 + j, o[i][yb][j]);
    }
}

extern "C" void kernel_launch(void* const* d_in, const int* in_sizes, int n_in,
                              void* d_out, int out_size, void* d_ws, size_t ws_size,
                              hipStream_t stream) {
    const float* X = (const float*)d_in[0];   // batch   [8192, 512]
    const float* Z = (const float*)d_in[1];   // centers [8192, 512]
    const float* W = (const float*)d_in[2];   // weight  [8192, 256]
    float* O = (float*)d_out;                 // pred    [8192, 256]

    hipMemsetAsync(d_out, 0, (size_t)out_size * sizeof(float), stream);

    if (ws_size < WS_NEED) {
        dim3 grid(Nn / FBM, FMCH);
        laplace_fused_v1<<<grid, dim3(256), 0, stream>>>(X, Z, W, O);
        return;
    }

    char* ws = (char*)d_ws;
    ushort* Xf  = (ushort*)(ws + OFF_XF);
    ushort* Zf  = (ushort*)(ws + OFF_ZF);
    ushort* Wf  = (ushort*)(ws + OFF_WF);
    float*  xsq = (float*)(ws + OFF_XSQ);
    float*  zsq = (float*)(ws + OFF_ZSQ);

    prep_v11<<<dim3(1024 + 256), dim3(256), 0, stream>>>(
        X, Z, W, Xf, Zf, Wf, xsq, zsq);

    laplace_v17<<<dim3(Nn / BM, MCH), dim3(256), 0, stream>>>(
        Xf, Zf, Wf, xsq, zsq, O);
}

// Round 7
// 206.108 us; speedup vs baseline: 2.3463x; 1.0522x over previous
//
#include <hip/hip_runtime.h>

// Laplacian-kernel regression, fused, bf16 MFMA 32x32x16.
//   d2 = ||x||^2 + ||z||^2 - 2 X.Z^T ; P = exp(-sqrt(d2)/10) ; out = P @ W
// R18: v12 (131us record: 32x32 MFMA, XCD-swizzled 1-D grid, R1 X-half
// persistent, R2 = X-h1/sP time-share, 31MB FETCH, 0 conflicts) with the
// prefetch lead fixed to cover L2 latency (~250cyc):
//  * zb depth-4 (lead 4 iters ~300cyc; was depth-2 ~100cyc -> ~150cyc stall
//    per kk = the measured 66% idle). Peak regs ~246 < 256 cap at (256,2).
//  * merged kw 0..31 QK loop: h0's tail refills (kw12..15 load kw16..19)
//    prefetch ACROSS the h1 barrier -> no exposed h1-entry loads.
//  * vmcnt(8) at kw16 (8 tail gloads oldest, in-order retirement) instead
//    of vmcnt(0) draining fresh refills; sched_barrier pins tail order.
//  * wb depth-4 preloaded after B1 -> W latency hides under transform;
//    wb reuses zb's dead registers (disjoint ranges).
// Structure, LDS (66,560B, 2 blk/CU), barriers (4/mt), grid, MFMA order
// all identical to v12 -> same absmax. Lessons kept: no >2 waves/SIMD
// (v13/v15 spill), no wave-tile shrink (v14 L2 doubling), no per-mt full-X
// restage (v16 FETCH blowup).

using frag8  = __attribute__((ext_vector_type(8)))  short;   // 8 bf16 (4 VGPRs)
using f32x16 = __attribute__((ext_vector_type(16))) float;   // 32x32 C/D frag

constexpr int Nn = 8192, Mm = 8192, Dd = 512, Yd = 256;
constexpr int BM = 64, BN = 256;
constexpr int MCH = 4, MPER = Mm / MCH, MT = MPER / BN;    // 2048, 8
constexpr int LDP = BN + 8;    // 264 ushort row stride for sP

// Fragment-tile layout (16-row groups, prep_v11):
// frag(g, c) = rows [16g,16g+16) x k [32c,32c+32), 512 ushorts at
// (g*KG + c)*512, element (r,k) at ushort lane16*8 + k%8 where
// lane16 = r%16 + 16*((k%32)/8).  Xf/Zf: KG=16 (K=512). Wf: rows=y, KG=256.
// 32x32x16 A/B-frag for lane L (r=L&31, h=L>>5) = one 16B chunk at
// base + kw*256 ushorts (kw = 16-k window), base = g0*8192 + lane_lo.

// workspace layout (bytes)
constexpr size_t OFF_XF  = 0;                               // 8 MB
constexpr size_t OFF_ZF  = OFF_XF + (size_t)Nn * Dd * 2;    // 8 MB
constexpr size_t OFF_WF  = OFF_ZF + (size_t)Mm * Dd * 2;    // 4 MB
constexpr size_t OFF_XSQ = OFF_WF + (size_t)Yd * Mm * 2;
constexpr size_t OFF_ZSQ = OFF_XSQ + (size_t)Nn * 4;
constexpr size_t WS_NEED = OFF_ZSQ + (size_t)Mm * 4;        // ~20.1 MB

__device__ __forceinline__ ushort f2bf(float f) {
    unsigned u = __builtin_bit_cast(unsigned, f);
    u += 0x7FFFu + ((u >> 16) & 1u);          // RNE (prep only)
    return (ushort)(u >> 16);
}

__device__ __forceinline__ void gload_lds16(const ushort* g, ushort* l) {
    __builtin_amdgcn_global_load_lds(
        (const __attribute__((address_space(1))) unsigned int*)(g),
        (__attribute__((address_space(3))) unsigned int*)(l), 16, 0, 0);
}

// ---- prep (LDS-tiled, coalesced) — unchanged from v11 ----
__global__ __launch_bounds__(256) void prep_v11(
    const float* __restrict__ X, const float* __restrict__ Z,
    const float* __restrict__ W, ushort* __restrict__ Xf,
    ushort* __restrict__ Zf, ushort* __restrict__ Wf,
    float* __restrict__ xsq, float* __restrict__ zsq)
{
    __shared__ float tile[8320];                  // 16x517 (X/Z) or 32x260 (W)
    __shared__ float part[256];
    const int t = threadIdx.x, b = blockIdx.x;
    if (b < 1024) {
        const int g = (b < 512) ? b : b - 512;
        const float* src = (b < 512 ? X : Z) + (size_t)g * 16 * Dd;
        ushort* dst = (b < 512 ? Xf : Zf) + (size_t)g * 16 * 512;
        float* nrm = (b < 512 ? xsq : zsq) + g * 16;
        #pragma unroll
        for (int rep = 0; rep < 8; ++rep) {       // 2048 float4, coalesced
            const int idx = rep * 256 + t;
            const int r = idx >> 7, c4 = (idx & 127) * 4;
            const float4 v = *(const float4*)(src + (size_t)r * Dd + c4);
            float* d = tile + r * 517 + c4;
            d[0] = v.x; d[1] = v.y; d[2] = v.z; d[3] = v.w;
        }
        __syncthreads();
        {
            const int r = t & 15, s0 = (t >> 4) * 32;
            float sq = 0.0f;
            #pragma unroll
            for (int k = 0; k < 32; ++k) {
                const float v = tile[r * 517 + s0 + k];
                sq += v * v;
            }
            part[t] = sq;
        }
        __syncthreads();
        if (t < 16) {
            float sq = 0.0f;
            #pragma unroll
            for (int s = 0; s < 16; ++s) sq += part[t + 16 * s];
            nrm[t] = sq;
        }
        #pragma unroll
        for (int rep = 0; rep < 4; ++rep) {       // 1024 uint4 frag writes
            const int idx = rep * 256 + t;
            const int kg = idx >> 6, w = idx & 63;
            const int l16 = w & 15, quad = w >> 4;
            const float* s = tile + l16 * 517 + kg * 32 + quad * 8;
            uint4 pk;
            pk.x = (unsigned)f2bf(s[0]) | ((unsigned)f2bf(s[1]) << 16);
            pk.y = (unsigned)f2bf(s[2]) | ((unsigned)f2bf(s[3]) << 16);
            pk.z = (unsigned)f2bf(s[4]) | ((unsigned)f2bf(s[5]) << 16);
            pk.w = (unsigned)f2bf(s[6]) | ((unsigned)f2bf(s[7]) << 16);
            *(uint4*)(dst + (size_t)kg * 512 + w * 8) = pk;
        }
    } else {
        const int zg = b - 1024;                  // 32-z stripe of W
        const float* src = W + (size_t)zg * 32 * Yd;
        #pragma unroll
        for (int rep = 0; rep < 8; ++rep) {
            const int idx = rep * 256 + t;
            const int r = idx >> 6, c4 = (idx & 63) * 4;
            const float4 v = *(const float4*)(src + (size_t)r * Yd + c4);
            float* d = tile + r * 260 + c4;
            d[0] = v.x; d[1] = v.y; d[2] = v.z; d[3] = v.w;
        }
        __syncthreads();
        #pragma unroll
        for (int rep = 0; rep < 4; ++rep) {
            const int idx = rep * 256 + t;
            const int yg = idx >> 6, w = idx & 63;
            const int l16 = w & 15, quad = w >> 4;
            const int y = yg * 16 + l16;
            ushort rr[8];
            #pragma unroll
            for (int j = 0; j < 8; ++j)
                rr[j] = f2bf(tile[(quad * 8 + j) * 260 + y]);
            uint4 pk;
            pk.x = (unsigned)rr[0] | ((unsigned)rr[1] << 16);
            pk.y = (unsigned)rr[2] | ((unsigned)rr[3] << 16);
            pk.z = (unsigned)rr[4] | ((unsigned)rr[5] << 16);
            pk.w = (unsigned)rr[6] | ((unsigned)rr[7] << 16);
            *(uint4*)(Wf + ((size_t)yg * 256 + zg) * 512 + w * 8) = pk;
        }
    }
}

// ---- main fused kernel (v18): v12 + depth-4 prefetch + counted vmcnt ----
__global__ __launch_bounds__(256, 2) void laplace_v18(
    const ushort* __restrict__ Xf, const ushort* __restrict__ Zf,
    const ushort* __restrict__ Wf, const float* __restrict__ xsqg,
    const float* __restrict__ zsqg, float* __restrict__ O)
{
    __shared__ ushort sM[16384 + 16896];          // 66,560 B total
    ushort* R1 = sM;                              // X k[0,256): 32 units * 512
    ushort* R2 = sM + 16384;                      // X k[256,512) UNION sP[64][LDP]

    const int t = threadIdx.x, wid = t >> 6, lane = t & 63;
    const int l32 = lane & 31, hb = lane >> 5;

    // XCD-aware swizzle: z-chunk pinned to an XCD pair (grid = 512, 1-D)
    const int bid = blockIdx.x;
    const int xcd = bid & 7;
    const int chunk = xcd >> 1;                   // 0..3
    const int xi = ((xcd & 1) << 6) + (bid >> 3); // 0..127
    const int row0 = xi * BM;
    const int zbase = chunk * MPER;

    const unsigned lane_lo = (unsigned)(((l32 & 15) + 16 * hb) * 8);
    const unsigned xsrc_base =
        (unsigned)(((row0 >> 4) + (l32 >> 4)) * 8192) + lane_lo;

    // ---- prologue: stage R1 (kw 0..15) and R2 (kw 16..31) once ----
    #pragma unroll
    for (int q = 0; q < 8; ++q) {
        const int f = wid * 8 + q;                // 0..31
        const int kw = f >> 1, i = f & 1;
        const ushort* s1 = Xf + xsrc_base + (unsigned)i * 16384u
                              + (unsigned)kw * 256u;
        gload_lds16(s1,            R1 + f * 512);
        gload_lds16(s1 + 4096u,    R2 + f * 512);   // +16 k-windows
    }

    f32x16 Oa[2][2];
    #pragma unroll
    for (int i = 0; i < 2; ++i)
        #pragma unroll
        for (int j = 0; j < 2; ++j)
            #pragma unroll
            for (int r = 0; r < 16; ++r) Oa[i][j][r] = 0.0f;

    // Z stream state; zb depth-4 rolling
    unsigned zo0 = ((unsigned)((zbase >> 4) + wid * 4 + (l32 >> 4))) * 8192u
                   + lane_lo;
    unsigned zo1 = zo0 + 16384u;                  // +2 z 16-row groups (j=1)
    frag8 zb[4][2];
    #pragma unroll
    for (int p = 0; p < 4; ++p) {
        zb[p][0] = *(const frag8*)(Zf + zo0 + (unsigned)p * 256u);
        zb[p][1] = *(const frag8*)(Zf + zo1 + (unsigned)p * 256u);
    }

    asm volatile("s_waitcnt vmcnt(0)" ::: "memory");
    __syncthreads();                              // staging + zb complete

    unsigned zwg = (unsigned)(zbase >> 4);        // W z 16-group base
    const unsigned wyg = (unsigned)(wid * 4 + (l32 >> 4));
    const int pa0 = l32 * LDP + 8 * hb;

    #pragma unroll 1
    for (int mt = 0; mt < MT; ++mt) {
        const int zc0 = zbase + mt * 256 + wid * 64 + l32;
        const float zs0 = zsqg[zc0];
        const float zs1 = zsqg[zc0 + 32];

        f32x16 S[2][2];
        #pragma unroll
        for (int i = 0; i < 2; ++i)
            #pragma unroll
            for (int j = 0; j < 2; ++j)
                #pragma unroll
                for (int r = 0; r < 16; ++r) S[i][j][r] = 0.0f;

        // xa depth-2 from R1
        frag8 xa[2][2];
        #pragma unroll
        for (int p = 0; p < 2; ++p)
            #pragma unroll
            for (int i = 0; i < 2; ++i)
                xa[p][i] = *(const frag8*)(R1 + (2 * p + i) * 512 + lane * 8);

        // ---- QK: merged kw 0..31; h0 from R1, h1 from R2 ----
        #pragma unroll
        for (int kw = 0; kw < 32; ++kw) {
            if (kw == 16) {
                // R2 restage (8 oldest gloads) done; keep newest zb in flight
                asm volatile("s_waitcnt vmcnt(8)" ::: "memory");
                __syncthreads();
                #pragma unroll
                for (int p = 0; p < 2; ++p)
                    #pragma unroll
                    for (int i = 0; i < 2; ++i)
                        xa[p][i] = *(const frag8*)(
                            R2 + (2 * p + i) * 512 + lane * 8);
            }
            const int s = kw & 1, zs = kw & 3;
            __builtin_amdgcn_s_setprio(1);
            S[0][0] = __builtin_amdgcn_mfma_f32_32x32x16_bf16(
                xa[s][0], zb[zs][0], S[0][0], 0, 0, 0);
            S[0][1] = __builtin_amdgcn_mfma_f32_32x32x16_bf16(
                xa[s][0], zb[zs][1], S[0][1], 0, 0, 0);
            S[1][0] = __builtin_amdgcn_mfma_f32_32x32x16_bf16(
                xa[s][1], zb[zs][0], S[1][0], 0, 0, 0);
            S[1][1] = __builtin_amdgcn_mfma_f32_32x32x16_bf16(
                xa[s][1], zb[zs][1], S[1][1], 0, 0, 0);
            __builtin_amdgcn_s_setprio(0);
            // xa refill (depth-2); skip the pre-barrier boundary (re-init at 16)
            if (kw + 2 < 16) {
                #pragma unroll
                for (int i = 0; i < 2; ++i)
                    xa[s][i] = *(const frag8*)(
                        R1 + (2 * (kw + 2) + i) * 512 + lane * 8);
            } else if (kw >= 16 && kw + 2 < 32) {
                #pragma unroll
                for (int i = 0; i < 2; ++i)
                    xa[s][i] = *(const frag8*)(
                        R2 + (2 * (kw + 2 - 16) + i) * 512 + lane * 8);
            }
            // zb refill (depth-4) — crosses the kw16 barrier seamlessly
            if (kw + 4 < 32) {
                zb[zs][0] = *(const frag8*)(Zf + zo0
                                            + (unsigned)(kw + 4) * 256u);
                zb[zs][1] = *(const frag8*)(Zf + zo1
                                            + (unsigned)(kw + 4) * 256u);
            }
        }

        __syncthreads();   // B1: all waves done reading R2 (X h1)

        // ---- wb depth-4 preload (reuses zb's dead regs); lands under
        //      transform's ~1500cyc of VALU ----
        const unsigned wo0 = wyg * 131072u + zwg * 256u + lane_lo;
        frag8 wb[4][2];
        #pragma unroll
        for (int p = 0; p < 4; ++p) {
            wb[p][0] = *(const frag8*)(Wf + wo0 + (unsigned)p * 256u);
            wb[p][1] = *(const frag8*)(Wf + wo0 + 262144u
                                       + (unsigned)p * 256u);
        }

        // ---- transform S -> sP in R2 (C/D: col=l32, row=(r&3)+8*(r>>2)+4*hb)
        #pragma unroll
        for (int i = 0; i < 2; ++i) {
            float xv[16];
            #pragma unroll
            for (int g = 0; g < 4; ++g) {
                const float4 v =
                    *(const float4*)(xsqg + row0 + 32 * i + 8 * g + 4 * hb);
                xv[4 * g + 0] = v.x; xv[4 * g + 1] = v.y;
                xv[4 * g + 2] = v.z; xv[4 * g + 3] = v.w;
            }
            #pragma unroll
            for (int j = 0; j < 2; ++j) {
                const float zz = j ? zs1 : zs0;
                const int col = wid * 64 + 32 * j + l32;
                #pragma unroll
                for (int r = 0; r < 16; ++r) {
                    const int xrow = 32 * i + (r & 3) + 8 * (r >> 2) + 4 * hb;
                    const float xpz = xv[r] + zz;
                    float d2 = fmaf(S[i][j][r], -2.0f, xpz);
                    d2 = fmaxf(d2, 1e-20f);
                    const float dist = d2 * __frsqrt_rn(d2);     // sqrt(d2)
                    const float e = __builtin_amdgcn_exp2f(
                        dist * -0.14426950408889634f);           // exp(-dist/10)
                    R2[xrow * LDP + col] =
                        (ushort)(__builtin_bit_cast(unsigned, e) >> 16);
                }
            }
        }
        __syncthreads();   // B2: sP ready

        // ---- PV: O += P[64x256].W[256x256]; A from sP (R2), B = wb ----
        frag8 pa[2][2];
        #pragma unroll
        for (int p = 0; p < 2; ++p)
            #pragma unroll
            for (int i = 0; i < 2; ++i)
                pa[p][i] = *(const frag8*)(R2 + pa0 + i * 32 * LDP + p * 16);
        #pragma unroll
        for (int zw = 0; zw < 16; ++zw) {
            const int s2 = zw & 1, ws = zw & 3;
            __builtin_amdgcn_s_setprio(1);
            Oa[0][0] = __builtin_amdgcn_mfma_f32_32x32x16_bf16(
                pa[s2][0], wb[ws][0], Oa[0][0], 0, 0, 0);
            Oa[0][1] = __builtin_amdgcn_mfma_f32_32x32x16_bf16(
                pa[s2][0], wb[ws][1], Oa[0][1], 0, 0, 0);
            Oa[1][0] = __builtin_amdgcn_mfma_f32_32x32x16_bf16(
                pa[s2][1], wb[ws][0], Oa[1][0], 0, 0, 0);
            Oa[1][1] = __builtin_amdgcn_mfma_f32_32x32x16_bf16(
                pa[s2][1], wb[ws][1], Oa[1][1], 0, 0, 0);
            __builtin_amdgcn_s_setprio(0);
            if (zw + 2 < 16) {
                #pragma unroll
                for (int i = 0; i < 2; ++i)
                    pa[s2][i] = *(const frag8*)(
                        R2 + pa0 + i * 32 * LDP + (zw + 2) * 16);
            }
            if (zw + 4 < 16) {
                wb[ws][0] = *(const frag8*)(Wf + wo0
                                            + (unsigned)(zw + 4) * 256u);
                wb[ws][1] = *(const frag8*)(Wf + wo0 + 262144u
                                            + (unsigned)(zw + 4) * 256u);
            }
        }
        __syncthreads();   // B3: sP reads done, R2 free

        // ---- tail: restage X h1 (8 gloads, OLDEST); then next-mt zb ----
        if (mt + 1 < MT) {
            #pragma unroll
            for (int q = 0; q < 8; ++q) {
                const int f = wid * 8 + q;        // 0..31
                const int kw = (f >> 1) + 16, i = f & 1;
                gload_lds16(Xf + xsrc_base + (unsigned)i * 16384u
                               + (unsigned)kw * 256u,
                            R2 + f * 512);
            }
            __builtin_amdgcn_sched_barrier(0);    // pin order: gloads first
            zo0 += 131072u; zo1 += 131072u;
            #pragma unroll
            for (int p = 0; p < 4; ++p) {
                zb[p][0] = *(const frag8*)(Zf + zo0 + (unsigned)p * 256u);
                zb[p][1] = *(const frag8*)(Zf + zo1 + (unsigned)p * 256u);
            }
        }
        zwg += 16u;
    }

    // ---- epilogue: combine MCH=4 chunks via fp32 atomics (XCD-local) ----
    #pragma unroll
    for (int i = 0; i < 2; ++i)
        #pragma unroll
        for (int jy = 0; jy < 2; ++jy) {
            const int yg = wid * 64 + 32 * jy + l32;
            #pragma unroll
            for (int r = 0; r < 16; ++r) {
                const int xg = row0 + 32 * i + (r & 3) + 8 * (r >> 2) + 4 * hb;
                atomicAdd(&O[(size_t)xg * Yd + yg], Oa[i][jy][r]);
            }
        }
}

// ---- fallback (fp32 VALU fused kernel) if workspace is too small ----
constexpr int FBM = 64, FBN = 64, FBK = 64;
constexpr int FMCH = 4, FMCHUNK = Mm / FMCH, FMSTEPS = FMCHUNK / FBN, FDSTEPS = Dd / FBK;
constexpr int FLDA = FBK + 1, FLDSS = FBN + 1;

__global__ __launch_bounds__(256, 3) void laplace_fused_v1(
    const float* __restrict__ X, const float* __restrict__ Z,
    const float* __restrict__ W, float* __restrict__ O)
{
    __shared__ float sX[FBM * FLDA];
    __shared__ float sZ[FBN * FLDA];
    __shared__ float sS[FBM * FLDSS];
    const int t = threadIdx.x, pr = t >> 4, pc = t & 15, sc4 = pc * 4;
    const int row0 = blockIdx.x * FBM, mbase = blockIdx.y * FMCHUNK;
    float o[4][4][4];
    #pragma unroll
    for (int i = 0; i < 4; ++i)
        for (int yb = 0; yb < 4; ++yb)
            for (int j = 0; j < 4; ++j) o[i][yb][j] = 0.0f;
    for (int ms = 0; ms < FMSTEPS; ++ms) {
        const int zrow0 = mbase + ms * FBN;
        float s[4][4];
        #pragma unroll
        for (int i = 0; i < 4; ++i)
            for (int j = 0; j < 4; ++j) s[i][j] = 0.0f;
        for (int kk = 0; kk < FDSTEPS; ++kk) {
            const int k0 = kk * FBK;
            __syncthreads();
            #pragma unroll
            for (int rep = 0; rep < 4; ++rep) {
                const int r = pr + rep * 16;
                const float4 xv = *reinterpret_cast<const float4*>(X + (size_t)(row0 + r) * Dd + k0 + sc4);
                const float4 zv = *reinterpret_cast<const float4*>(Z + (size_t)(zrow0 + r) * Dd + k0 + sc4);
                float* dx = sX + r * FLDA + sc4;
                dx[0] = xv.x; dx[1] = xv.y; dx[2] = xv.z; dx[3] = xv.w;
                float* dz = sZ + r * FLDA + sc4;
                dz[0] = zv.x; dz[1] = zv.y; dz[2] = zv.z; dz[3] = zv.w;
            }
            __syncthreads();
            #pragma unroll 4
            for (int k = 0; k < FBK; ++k) {
                float xr[4], zc[4];
                #pragma unroll
                for (int i = 0; i < 4; ++i) xr[i] = sX[(pr * 4 + i) * FLDA + k];
                #pragma unroll
                for (int j = 0; j < 4; ++j) zc[j] = sZ[(pc * 4 + j) * FLDA + k];
                #pragma unroll
                for (int i = 0; i < 4; ++i)
                    #pragma unroll
                    for (int j = 0; j < 4; ++j) {
                        const float d = xr[i] - zc[j];
                        s[i][j] = fmaf(d, d, s[i][j]);
                    }
            }
        }
        #pragma unroll
        for (int i = 0; i < 4; ++i)
            for (int j = 0; j < 4; ++j)
                sS[(pr * 4 + i) * FLDSS + sc4 + j] = __expf(-sqrtf(s[i][j]) * 0.1f);
        __syncthreads();
        #pragma unroll 2
        for (int c = 0; c < FBN; ++c) {
            float sv[4];
            #pragma unroll
            for (int i = 0; i < 4; ++i) sv[i] = sS[(pr * 4 + i) * FLDSS + c];
            const float* wrow = W + (size_t)(zrow0 + c) * Yd;
            #pragma unroll
            for (int yb = 0; yb < 4; ++yb) {
                const float4 wv = *reinterpret_cast<const float4*>(wrow + yb * 64 + sc4);
                #pragma unroll
                for (int i = 0; i < 4; ++i) {
                    o[i][yb][0] = fmaf(sv[i], wv.x, o[i][yb][0]);
                    o[i][yb][1] = fmaf(sv[i], wv.y, o[i][yb][1]);
                    o[i][yb][2] = fmaf(sv[i], wv.z, o[i][yb][2]);
                    o[i][yb][3] = fmaf(sv[i], wv.w, o[i][yb][3]);
                }
            }
        }
        __syncthreads();
    }
    #pragma unroll
    for (int i = 0; i < 4; ++i) {
        const size_t rbase = (size_t)(row0 + pr * 4 + i) * Yd;
        #pragma unroll
        for (int yb = 0; yb < 4; ++yb)
            for (int j = 0; j < 4; ++j)
                atomicAdd(O + rbase + yb * 64 + sc4 + j, o[i][yb][j]);
    }
}

extern "C" void kernel_launch(void* const* d_in, const int* in_sizes, int n_in,
                              void* d_out, int out_size, void* d_ws, size_t ws_size,
                              hipStream_t stream) {
    const float* X = (const float*)d_in[0];   // batch   [8192, 512]
    const float* Z = (const float*)d_in[1];   // centers [8192, 512]
    const float* W = (const float*)d_in[2];   // weight  [8192, 256]
    float* O = (float*)d_out;                 // pred    [8192, 256]

    hipMemsetAsync(d_out, 0, (size_t)out_size * sizeof(float), stream);

    if (ws_size < WS_NEED) {
        dim3 grid(Nn / FBM, FMCH);
        laplace_fused_v1<<<grid, dim3(256), 0, stream>>>(X, Z, W, O);
        return;
    }

    char* ws = (char*)d_ws;
    ushort* Xf  = (ushort*)(ws + OFF_XF);
    ushort* Zf  = (ushort*)(ws + OFF_ZF);
    ushort* Wf  = (ushort*)(ws + OFF_WF);
    float*  xsq = (float*)(ws + OFF_XSQ);
    float*  zsq = (float*)(ws + OFF_ZSQ);

    prep_v11<<<dim3(1024 + 256), dim3(256), 0, stream>>>(
        X, Z, W, Xf, Zf, Wf, xsq, zsq);

    laplace_v18<<<dim3(512), dim3(256), 0, stream>>>(
        Xf, Zf, Wf, xsq, zsq, O);
}